// Round 6
// baseline (199.537 us; speedup 1.0000x reference)
//
#include <hip/hip_runtime.h>
#include <math.h>

// Volume dims (fixed by the problem: IMG_SHAPE = (256,256,256))
#define DD 256
#define HH 256
#define WW 256
#define TS 16          // output tile edge (16^3 voxels per block)
#define LDSF 16384     // LDS floats for staged input box (64 KB)

typedef float f2v __attribute__((ext_vector_type(2)));
typedef f2v __attribute__((aligned(4))) f2u;
typedef float f4v __attribute__((ext_vector_type(4)));
typedef f4v __attribute__((aligned(4))) f4u;

// ---------------------------------------------------------------------------
// Kernel 1: one thread computes the 3x4 resampling transform
// T = rows 0..2 of inv(flo_v2r) @ T_rig @ ref_v2r -> 12 floats in d_ws.
// ---------------------------------------------------------------------------
__global__ void compute_T_kernel(const float* __restrict__ angle,
                                 const float* __restrict__ trans,
                                 const float* __restrict__ ref_v2r,
                                 const float* __restrict__ flo_v2r,
                                 const float* __restrict__ cog,
                                 float* __restrict__ Tout /* 12 floats */) {
    if (blockIdx.x != 0 || threadIdx.x != 0) return;

    const float ax = angle[0], ay = angle[1], az = angle[2];
    const float cx = cosf(ax), sx = sinf(ax);
    const float cy = cosf(ay), sy = sinf(ay);
    const float cz = cosf(az), sz = sinf(az);

    // R = Rx @ Ry @ Rz ;  Rx@Ry = [[cy,0,sy],[sx*sy,cx,-sx*cy],[-cx*sy,sx,cx*cy]]
    float R[3][3];
    const float a00 = cy,       a01 = 0.0f, a02 = sy;
    const float a10 = sx * sy,  a11 = cx,   a12 = -sx * cy;
    const float a20 = -cx * sy, a21 = sx,   a22 = cx * cy;
    R[0][0] = a00 * cz + a01 * sz; R[0][1] = -a00 * sz + a01 * cz; R[0][2] = a02;
    R[1][0] = a10 * cz + a11 * sz; R[1][1] = -a10 * sz + a11 * cz; R[1][2] = a12;
    R[2][0] = a20 * cz + a21 * sz; R[2][1] = -a20 * sz + a21 * cz; R[2][2] = a22;

    // T_rig: linear part R, translation cog + t - R@cog
    float Trig[4][4];
    for (int r = 0; r < 4; ++r)
        for (int c = 0; c < 4; ++c)
            Trig[r][c] = (r == c) ? 1.0f : 0.0f;
    for (int r = 0; r < 3; ++r) {
        for (int c = 0; c < 3; ++c) Trig[r][c] = R[r][c];
        Trig[r][3] = cog[r] + trans[r]
                   - (R[r][0] * cog[0] + R[r][1] * cog[1] + R[r][2] * cog[2]);
    }

    // Closed-form 4x4 inverse of flo_v2r (adjugate).
    float m[16], inv[16];
    for (int q = 0; q < 16; ++q) m[q] = flo_v2r[q];
    inv[0]  =  m[5]*m[10]*m[15] - m[5]*m[11]*m[14] - m[9]*m[6]*m[15]
             + m[9]*m[7]*m[14] + m[13]*m[6]*m[11] - m[13]*m[7]*m[10];
    inv[4]  = -m[4]*m[10]*m[15] + m[4]*m[11]*m[14] + m[8]*m[6]*m[15]
             - m[8]*m[7]*m[14] - m[12]*m[6]*m[11] + m[12]*m[7]*m[10];
    inv[8]  =  m[4]*m[9]*m[15] - m[4]*m[11]*m[13] - m[8]*m[5]*m[15]
             + m[8]*m[7]*m[13] + m[12]*m[5]*m[11] - m[12]*m[7]*m[9];
    inv[12] = -m[4]*m[9]*m[14] + m[4]*m[10]*m[13] + m[8]*m[5]*m[14]
             - m[8]*m[6]*m[13] - m[12]*m[5]*m[10] + m[12]*m[6]*m[9];
    inv[1]  = -m[1]*m[10]*m[15] + m[1]*m[11]*m[14] + m[9]*m[2]*m[15]
             - m[9]*m[3]*m[14] - m[13]*m[2]*m[11] + m[13]*m[3]*m[10];
    inv[5]  =  m[0]*m[10]*m[15] - m[0]*m[11]*m[14] - m[8]*m[2]*m[15]
             + m[8]*m[3]*m[14] + m[12]*m[2]*m[11] - m[12]*m[3]*m[10];
    inv[9]  = -m[0]*m[9]*m[15] + m[0]*m[11]*m[13] + m[8]*m[1]*m[15]
             - m[8]*m[3]*m[13] - m[12]*m[1]*m[11] + m[12]*m[3]*m[9];
    inv[13] =  m[0]*m[9]*m[14] - m[0]*m[10]*m[13] - m[8]*m[1]*m[14]
             + m[8]*m[2]*m[13] + m[12]*m[1]*m[10] - m[12]*m[2]*m[9];
    inv[2]  =  m[1]*m[6]*m[15] - m[1]*m[7]*m[14] - m[5]*m[2]*m[15]
             + m[5]*m[3]*m[14] + m[13]*m[2]*m[7] - m[13]*m[3]*m[6];
    inv[6]  = -m[0]*m[6]*m[15] + m[0]*m[7]*m[14] + m[4]*m[2]*m[15]
             - m[4]*m[3]*m[14] - m[12]*m[2]*m[7] + m[12]*m[3]*m[6];
    inv[10] =  m[0]*m[5]*m[15] - m[0]*m[7]*m[13] - m[4]*m[1]*m[15]
             + m[4]*m[3]*m[13] + m[12]*m[1]*m[7] - m[12]*m[3]*m[5];
    inv[14] = -m[0]*m[5]*m[14] + m[0]*m[6]*m[13] + m[4]*m[1]*m[14]
             - m[4]*m[2]*m[13] - m[12]*m[1]*m[6] + m[12]*m[2]*m[5];
    inv[3]  = -m[1]*m[6]*m[11] + m[1]*m[7]*m[10] + m[5]*m[2]*m[11]
             - m[5]*m[3]*m[10] - m[9]*m[2]*m[7] + m[9]*m[3]*m[6];
    inv[7]  =  m[0]*m[6]*m[11] - m[0]*m[7]*m[10] - m[4]*m[2]*m[11]
             + m[4]*m[3]*m[10] + m[8]*m[2]*m[7] - m[8]*m[3]*m[6];
    inv[11] = -m[0]*m[5]*m[11] + m[0]*m[7]*m[9] + m[4]*m[1]*m[11]
             - m[4]*m[3]*m[9] - m[8]*m[1]*m[7] + m[8]*m[3]*m[5];
    inv[15] =  m[0]*m[5]*m[10] - m[0]*m[6]*m[9] - m[4]*m[1]*m[10]
             + m[4]*m[2]*m[9] + m[8]*m[1]*m[6] - m[8]*m[2]*m[5];
    const float det = m[0]*inv[0] + m[1]*inv[4] + m[2]*inv[8] + m[3]*inv[12];
    const float rdet = 1.0f / det;

    // M1 = Trig @ ref_v2r ; T = invF @ M1 ; rows 0..2 out
    float M1[4][4];
    for (int r = 0; r < 4; ++r)
        for (int c = 0; c < 4; ++c) {
            float s = 0.0f;
            for (int q = 0; q < 4; ++q) s += Trig[r][q] * ref_v2r[q * 4 + c];
            M1[r][c] = s;
        }
    for (int r = 0; r < 3; ++r)
        for (int c = 0; c < 4; ++c) {
            float s = 0.0f;
            for (int q = 0; q < 4; ++q) s += (inv[r * 4 + q] * rdet) * M1[q][c];
            Tout[r * 4 + c] = s;
        }
}

// ---------------------------------------------------------------------------
// Kernel 2: trilinear warp via LDS-STAGED TILES.
//
// R5..R11 post-mortem: duration pinned at 88-109us across MLP 8-32/wave,
// occupancy 10-60%, with/without software pipelining => saturated per-CU
// VMEM front-end (TA per-lane address processing / L1 tags / MSHRs) on the
// 1.05M scattered 64-lane gather instructions (4 per voxel, ~5-8 lines
// each). Scheduling cannot fix it; the gathers must go.
//
// R12: 16^3 output tile per block. Block computes the input bbox of its
// tile under T (8 affine corners, padded -1/+2 for the <=1e-4 rounding
// drift of the incremental per-voxel coords, clamped to the volume),
// stages that box into LDS with dense dwordx4 loads, barriers, then all
// 8 corner reads per voxel are LDS pair-reads. Per-voxel coordinate /
// weight / mask / lerp arithmetic is VERBATIM R10/R11 (anchors at i
// multiples of 4 + <=3 sequential adds) -> bit-identical output.
// Block-uniform `fits` check (box <= 16384 floats && Sk <= 32; guaranteed
// for pure-rotation T but guarded) falls back to the R8-style global path.
// ---------------------------------------------------------------------------
__global__ __launch_bounds__(256) void warp_kernel(
        const float* __restrict__ vol,
        const float* __restrict__ T,
        float* __restrict__ out) {
    // Wave-uniform scalar loads of the transform.
    const float t0 = T[0],  t1 = T[1],  t2  = T[2],  t3  = T[3];
    const float t4 = T[4],  t5 = T[5],  t6  = T[6],  t7  = T[7];
    const float t8 = T[8],  t9 = T[9],  t10 = T[10], t11 = T[11];

    // XCD brick mapping: xcd -> 2x2x2 brick of 128^3; 8x8x8 tiles per brick.
    const int bid = blockIdx.x;
    const int xcd = bid & 7;
    const int n = bid >> 3;              // 0..511 per brick
    const int bi = (xcd >> 2) & 1;
    const int bj = (xcd >> 1) & 1;
    const int bk = xcd & 1;
    const int kt = n & 7;
    const int jt = (n >> 3) & 7;
    const int it = n >> 6;               // 0..7

    const int i0 = (bi << 7) + (it << 4);
    const int j0 = (bj << 7) + (jt << 4);
    const int k0 = (bk << 7) + (kt << 4);

    const int tid = threadIdx.x;
    const int kl = tid & 15;             // k within tile (wave: 16k x 4j)
    const int jl = tid >> 4;             // j within tile
    const int j = j0 + jl;
    const int k = k0 + kl;
    const float gj = (float)j, gk = (float)k;
    const int out_base = (i0 << 16) + (j << 8) + k;

    __shared__ float sv[LDSF];

    // ---- input bbox of this tile (block-uniform; affine => corners bound) --
    float mni =  1e30f, mxi = -1e30f;
    float mnj =  1e30f, mxj = -1e30f;
    float mnk =  1e30f, mxk = -1e30f;
#pragma unroll
    for (int c = 0; c < 8; ++c) {
        const float ci_ = (float)(i0 + ((c & 1) ? (TS - 1) : 0));
        const float cj_ = (float)(j0 + ((c & 2) ? (TS - 1) : 0));
        const float ck_ = (float)(k0 + ((c & 4) ? (TS - 1) : 0));
        const float di = t0 * ci_ + t1 * cj_ + t2  * ck_ + t3;
        const float dj = t4 * ci_ + t5 * cj_ + t6  * ck_ + t7;
        const float dk = t8 * ci_ + t9 * cj_ + t10 * ck_ + t11;
        mni = fminf(mni, di); mxi = fmaxf(mxi, di);
        mnj = fminf(mnj, dj); mxj = fmaxf(mxj, dj);
        mnk = fminf(mnk, dk); mxk = fmaxf(mxk, dk);
    }
    // clamp -> floor -> pad (-1 / +2 absorbs incremental-rounding drift and
    // the ceil corner + k-pair +1). lo<=252 and hi>=lo+3 keep spans >=4.
    int lo_i = (int)fminf(fmaxf(mni, 0.0f), 255.0f);
    int hi_i = (int)fminf(fmaxf(mxi, 0.0f), 255.0f);
    int lo_j = (int)fminf(fmaxf(mnj, 0.0f), 255.0f);
    int hi_j = (int)fminf(fmaxf(mxj, 0.0f), 255.0f);
    int lo_k = (int)fminf(fmaxf(mnk, 0.0f), 255.0f);
    int hi_k = (int)fminf(fmaxf(mxk, 0.0f), 255.0f);
    lo_i = min(max(lo_i - 1, 0), 252);
    lo_j = min(max(lo_j - 1, 0), 252);
    lo_k = min(max(lo_k - 1, 0), 252);
    hi_i = min(max(hi_i + 2, lo_i + 3), 255);
    hi_j = min(max(hi_j + 2, lo_j + 3), 255);
    hi_k = min(max(hi_k + 2, lo_k + 3), 255);
    const int Si = hi_i - lo_i + 1;
    const int Sj = hi_j - lo_j + 1;
    const int Sk = hi_k - lo_k + 1;
    const int SjSk = Sj * Sk;
    const bool fits = (Si * SjSk <= LDSF) && (Sk <= 32);

    if (fits) {
        // ---------------- stage box into LDS (dense dwordx4) ----------------
        {
            const int kk0 = (tid & 7) << 2;  // 0,4,...,28 (covers Sk<=32)
            const int rj  = tid >> 3;        // 0..31 j-rows
            if (rj < Sj && kk0 < Sk) {
                const int kk = min(kk0, Sk - 4);   // overlap-tail (Sk>=4)
                const float* gp = vol + ((lo_i << 16) + ((lo_j + rj) << 8)
                                         + lo_k + kk);
                float* sp = sv + rj * Sk + kk;
                for (int li = 0; li < Si; ++li, gp += 65536, sp += SjSk) {
                    const f4v p = *(const f4u*)gp;
                    *(f4u*)sp = p;
                }
            }
        }
        __syncthreads();

        // ------------- interp: 4 groups of 4 i-voxels (verbatim R10) --------
#pragma unroll
        for (int IT = 0; IT < 4; ++IT) {
            const float gi_ = (float)(i0 + IT * 4);
            float di_ = t0 * gi_ + t1 * gj + t2  * gk + t3;
            float dj_ = t4 * gi_ + t5 * gj + t6  * gk + t7;
            float dk_ = t8 * gi_ + t9 * gj + t10 * gk + t11;
#pragma unroll
            for (int s_ = 0; s_ < 4; ++s_) {
                const float cdi = fminf(fmaxf(di_, 0.0f), (float)(DD - 1));
                const float cdj = fminf(fmaxf(dj_, 0.0f), (float)(HH - 1));
                const float cdk = fminf(fmaxf(dk_, 0.0f), (float)(WW - 1));
                const int fi = (int)cdi;
                const int fj = (int)cdj;
                const int fk = (int)cdk;
                const int ci = min(fi + 1, DD - 1);
                const int cj = min(fj + 1, HH - 1);
                const int pk = min(fk, WW - 2);
                const float wi = cdi - (float)fi;
                const float wj = cdj - (float)fj;
                const float wk = cdk - (float)pk;
                const bool ok_ = (di_ >= 0.0f) & (di_ <= (float)(DD - 1)) &
                                 (dj_ >= 0.0f) & (dj_ <= (float)(HH - 1)) &
                                 (dk_ >= 0.0f) & (dk_ <= (float)(WW - 1));

                const int o_fi = (fi - lo_i) * SjSk;
                const int o_ci = (ci - lo_i) * SjSk;
                const int o_fj = (fj - lo_j) * Sk;
                const int o_cj = (cj - lo_j) * Sk;
                const int pl = pk - lo_k;

                const f2v v0 = *(const f2u*)(sv + o_fi + o_fj + pl);
                const f2v v1 = *(const f2u*)(sv + o_fi + o_cj + pl);
                const f2v v2 = *(const f2u*)(sv + o_ci + o_fj + pl);
                const f2v v3 = *(const f2u*)(sv + o_ci + o_cj + pl);

                const float c00 = v0.x + (v0.y - v0.x) * wk;
                const float c01 = v1.x + (v1.y - v1.x) * wk;
                const float c10 = v2.x + (v2.y - v2.x) * wk;
                const float c11 = v3.x + (v3.y - v3.x) * wk;
                const float c0  = c00 + (c01 - c00) * wj;
                const float c1  = c10 + (c11 - c10) * wj;
                const float val = c0 + (c1 - c0) * wi;

                __builtin_nontemporal_store(ok_ ? val : 0.0f,
                    &out[out_base + ((IT * 4 + s_) << 16)]);

                di_ += t0; dj_ += t4; dk_ += t8;
            }
        }
    } else {
        // --------- fallback: per-voxel global gather (R8-style, verbatim) ---
#pragma unroll
        for (int IT = 0; IT < 4; ++IT) {
            const float gi_ = (float)(i0 + IT * 4);
            float di_ = t0 * gi_ + t1 * gj + t2  * gk + t3;
            float dj_ = t4 * gi_ + t5 * gj + t6  * gk + t7;
            float dk_ = t8 * gi_ + t9 * gj + t10 * gk + t11;
#pragma unroll
            for (int s_ = 0; s_ < 4; ++s_) {
                const float cdi = fminf(fmaxf(di_, 0.0f), (float)(DD - 1));
                const float cdj = fminf(fmaxf(dj_, 0.0f), (float)(HH - 1));
                const float cdk = fminf(fmaxf(dk_, 0.0f), (float)(WW - 1));
                const int fi = (int)cdi;
                const int fj = (int)cdj;
                const int fk = (int)cdk;
                const int ci = min(fi + 1, DD - 1);
                const int cj = min(fj + 1, HH - 1);
                const int pk = min(fk, WW - 2);
                const float wi = cdi - (float)fi;
                const float wj = cdj - (float)fj;
                const float wk = cdk - (float)pk;
                const bool ok_ = (di_ >= 0.0f) & (di_ <= (float)(DD - 1)) &
                                 (dj_ >= 0.0f) & (dj_ <= (float)(HH - 1)) &
                                 (dk_ >= 0.0f) & (dk_ <= (float)(WW - 1));

                const int fi_o = fi << 16, ci_o = ci << 16;
                const int fj_o = fj << 8,  cj_o = cj << 8;
                const f2v v0 = *(const f2u*)(vol + (fi_o + fj_o + pk));
                const f2v v1 = *(const f2u*)(vol + (fi_o + cj_o + pk));
                const f2v v2 = *(const f2u*)(vol + (ci_o + fj_o + pk));
                const f2v v3 = *(const f2u*)(vol + (ci_o + cj_o + pk));

                const float c00 = v0.x + (v0.y - v0.x) * wk;
                const float c01 = v1.x + (v1.y - v1.x) * wk;
                const float c10 = v2.x + (v2.y - v2.x) * wk;
                const float c11 = v3.x + (v3.y - v3.x) * wk;
                const float c0  = c00 + (c01 - c00) * wj;
                const float c1  = c10 + (c11 - c10) * wj;
                const float val = c0 + (c1 - c0) * wi;

                __builtin_nontemporal_store(ok_ ? val : 0.0f,
                    &out[out_base + ((IT * 4 + s_) << 16)]);

                di_ += t0; dj_ += t4; dk_ += t8;
            }
        }
    }
}

extern "C" void kernel_launch(void* const* d_in, const int* in_sizes, int n_in,
                              void* d_out, int out_size, void* d_ws, size_t ws_size,
                              hipStream_t stream) {
    const float* image_targ  = (const float*)d_in[0];
    const float* angle       = (const float*)d_in[1];
    const float* translation = (const float*)d_in[2];
    const float* ref_v2r     = (const float*)d_in[3];
    const float* flo_v2r     = (const float*)d_in[4];
    const float* cog         = (const float*)d_in[5];
    float* out = (float*)d_out;
    float* Tws = (float*)d_ws;   // 12 floats

    compute_T_kernel<<<1, 64, 0, stream>>>(angle, translation, ref_v2r,
                                           flo_v2r, cog, Tws);
    // 4096 blocks: 8 bricks x (8x8x8 tiles of 16^3).
    warp_kernel<<<(DD / TS) * (HH / TS) * (WW / TS), 256, 0, stream>>>(
        image_targ, Tws, out);
}

// Round 7
// 170.396 us; speedup vs baseline: 1.1710x; 1.1710x over previous
//
#include <hip/hip_runtime.h>
#include <math.h>

// Volume dims (fixed by the problem: IMG_SHAPE = (256,256,256))
#define DD 256
#define HH 256
#define WW 256
#define TI 16          // output tile extent in i
#define TJ 8           // output tile extent in j
#define TK 16          // output tile extent in k
#define LDSF 8192      // LDS floats for staged input box (32 KB -> 5 blocks/CU)

typedef float f2v __attribute__((ext_vector_type(2)));
typedef f2v __attribute__((aligned(4))) f2u;
typedef float f4v __attribute__((ext_vector_type(4)));
typedef f4v __attribute__((aligned(4))) f4u;

// ---------------------------------------------------------------------------
// Kernel 1: one thread computes the 3x4 resampling transform
// T = rows 0..2 of inv(flo_v2r) @ T_rig @ ref_v2r -> 12 floats in d_ws.
// ---------------------------------------------------------------------------
__global__ void compute_T_kernel(const float* __restrict__ angle,
                                 const float* __restrict__ trans,
                                 const float* __restrict__ ref_v2r,
                                 const float* __restrict__ flo_v2r,
                                 const float* __restrict__ cog,
                                 float* __restrict__ Tout /* 12 floats */) {
    if (blockIdx.x != 0 || threadIdx.x != 0) return;

    const float ax = angle[0], ay = angle[1], az = angle[2];
    const float cx = cosf(ax), sx = sinf(ax);
    const float cy = cosf(ay), sy = sinf(ay);
    const float cz = cosf(az), sz = sinf(az);

    // R = Rx @ Ry @ Rz ;  Rx@Ry = [[cy,0,sy],[sx*sy,cx,-sx*cy],[-cx*sy,sx,cx*cy]]
    float R[3][3];
    const float a00 = cy,       a01 = 0.0f, a02 = sy;
    const float a10 = sx * sy,  a11 = cx,   a12 = -sx * cy;
    const float a20 = -cx * sy, a21 = sx,   a22 = cx * cy;
    R[0][0] = a00 * cz + a01 * sz; R[0][1] = -a00 * sz + a01 * cz; R[0][2] = a02;
    R[1][0] = a10 * cz + a11 * sz; R[1][1] = -a10 * sz + a11 * cz; R[1][2] = a12;
    R[2][0] = a20 * cz + a21 * sz; R[2][1] = -a20 * sz + a21 * cz; R[2][2] = a22;

    // T_rig: linear part R, translation cog + t - R@cog
    float Trig[4][4];
    for (int r = 0; r < 4; ++r)
        for (int c = 0; c < 4; ++c)
            Trig[r][c] = (r == c) ? 1.0f : 0.0f;
    for (int r = 0; r < 3; ++r) {
        for (int c = 0; c < 3; ++c) Trig[r][c] = R[r][c];
        Trig[r][3] = cog[r] + trans[r]
                   - (R[r][0] * cog[0] + R[r][1] * cog[1] + R[r][2] * cog[2]);
    }

    // Closed-form 4x4 inverse of flo_v2r (adjugate).
    float m[16], inv[16];
    for (int q = 0; q < 16; ++q) m[q] = flo_v2r[q];
    inv[0]  =  m[5]*m[10]*m[15] - m[5]*m[11]*m[14] - m[9]*m[6]*m[15]
             + m[9]*m[7]*m[14] + m[13]*m[6]*m[11] - m[13]*m[7]*m[10];
    inv[4]  = -m[4]*m[10]*m[15] + m[4]*m[11]*m[14] + m[8]*m[6]*m[15]
             - m[8]*m[7]*m[14] - m[12]*m[6]*m[11] + m[12]*m[7]*m[10];
    inv[8]  =  m[4]*m[9]*m[15] - m[4]*m[11]*m[13] - m[8]*m[5]*m[15]
             + m[8]*m[7]*m[13] + m[12]*m[5]*m[11] - m[12]*m[7]*m[9];
    inv[12] = -m[4]*m[9]*m[14] + m[4]*m[10]*m[13] + m[8]*m[5]*m[14]
             - m[8]*m[6]*m[13] - m[12]*m[5]*m[10] + m[12]*m[6]*m[9];
    inv[1]  = -m[1]*m[10]*m[15] + m[1]*m[11]*m[14] + m[9]*m[2]*m[15]
             - m[9]*m[3]*m[14] - m[13]*m[2]*m[11] + m[13]*m[3]*m[10];
    inv[5]  =  m[0]*m[10]*m[15] - m[0]*m[11]*m[14] - m[8]*m[2]*m[15]
             + m[8]*m[3]*m[14] + m[12]*m[2]*m[11] - m[12]*m[3]*m[10];
    inv[9]  = -m[0]*m[9]*m[15] + m[0]*m[11]*m[13] + m[8]*m[1]*m[15]
             - m[8]*m[3]*m[13] - m[12]*m[1]*m[11] + m[12]*m[3]*m[9];
    inv[13] =  m[0]*m[9]*m[14] - m[0]*m[10]*m[13] - m[8]*m[1]*m[14]
             + m[8]*m[2]*m[13] + m[12]*m[1]*m[10] - m[12]*m[2]*m[9];
    inv[2]  =  m[1]*m[6]*m[15] - m[1]*m[7]*m[14] - m[5]*m[2]*m[15]
             + m[5]*m[3]*m[14] + m[13]*m[2]*m[7] - m[13]*m[3]*m[6];
    inv[6]  = -m[0]*m[6]*m[15] + m[0]*m[7]*m[14] + m[4]*m[2]*m[15]
             - m[4]*m[3]*m[14] - m[12]*m[2]*m[7] + m[12]*m[3]*m[6];
    inv[10] =  m[0]*m[5]*m[15] - m[0]*m[7]*m[13] - m[4]*m[1]*m[15]
             + m[4]*m[3]*m[13] + m[12]*m[1]*m[7] - m[12]*m[3]*m[5];
    inv[14] = -m[0]*m[5]*m[14] + m[0]*m[6]*m[13] + m[4]*m[1]*m[14]
             - m[4]*m[2]*m[13] - m[12]*m[1]*m[6] + m[12]*m[2]*m[5];
    inv[3]  = -m[1]*m[6]*m[11] + m[1]*m[7]*m[10] + m[5]*m[2]*m[11]
             - m[5]*m[3]*m[10] - m[9]*m[2]*m[7] + m[9]*m[3]*m[6];
    inv[7]  =  m[0]*m[6]*m[11] - m[0]*m[7]*m[10] - m[4]*m[2]*m[11]
             + m[4]*m[3]*m[10] + m[8]*m[2]*m[7] - m[8]*m[3]*m[6];
    inv[11] = -m[0]*m[5]*m[11] + m[0]*m[7]*m[9] + m[4]*m[1]*m[11]
             - m[4]*m[3]*m[9] - m[8]*m[1]*m[7] + m[8]*m[3]*m[5];
    inv[15] =  m[0]*m[5]*m[10] - m[0]*m[6]*m[9] - m[4]*m[1]*m[10]
             + m[4]*m[2]*m[9] + m[8]*m[1]*m[6] - m[8]*m[2]*m[5];
    const float det = m[0]*inv[0] + m[1]*inv[4] + m[2]*inv[8] + m[3]*inv[12];
    const float rdet = 1.0f / det;

    // M1 = Trig @ ref_v2r ; T = invF @ M1 ; rows 0..2 out
    float M1[4][4];
    for (int r = 0; r < 4; ++r)
        for (int c = 0; c < 4; ++c) {
            float s = 0.0f;
            for (int q = 0; q < 4; ++q) s += Trig[r][q] * ref_v2r[q * 4 + c];
            M1[r][c] = s;
        }
    for (int r = 0; r < 3; ++r)
        for (int c = 0; c < 4; ++c) {
            float s = 0.0f;
            for (int q = 0; q < 4; ++q) s += (inv[r * 4 + q] * rdet) * M1[q][c];
            Tout[r * 4 + c] = s;
        }
}

// ---------------------------------------------------------------------------
// Kernel 2: trilinear warp via LDS-staged tiles, v2.
//
// R5-R11: global-gather floor ~88-109us. Revised model: 4096 wave-gathers/CU
//   x 64 lanes ~= 262K cy ~= 109us @ ~1 addr/cy/CU -> per-lane address
//   processing is the wall. LDS tiling removes it.
// R12 (v1, 16^3 tile, 64KB LDS): 131us. Overheads localized by counters:
//   9.1M bank-conflict cycles (unpitched rows), 2 blocks/CU (64KB LDS, occ
//   20% -> no stage/consume overlap), 64B-run write inflation (minor).
// R13 (this): tile 16i x 8j x 16k, 32KB LDS -> 5 blocks/CU; pitched rows
//   Pk === 4 (mod 8) -> consume j-groups hit distinct banks, staging b128
//   writes <=2-way (free, m136); 2-deep staging load pipeline; all LDS
//   writes 16B-aligned (chunk grid at 4-float offsets, SkL=ceil4(Sk), with
//   k-window shift guard so global reads never go OOB). Consume arithmetic
//   VERBATIM R10/R12 (anchors at absolute-i multiples of 4) -> bit-exact.
//   Block-uniform fits guard falls back to verbatim global-gather path.
// ---------------------------------------------------------------------------
__global__ __launch_bounds__(256) void warp_kernel(
        const float* __restrict__ vol,
        const float* __restrict__ T,
        float* __restrict__ out) {
    // Wave-uniform scalar loads of the transform.
    const float t0 = T[0],  t1 = T[1],  t2  = T[2],  t3  = T[3];
    const float t4 = T[4],  t5 = T[5],  t6  = T[6],  t7  = T[7];
    const float t8 = T[8],  t9 = T[9],  t10 = T[10], t11 = T[11];

    // XCD brick mapping: xcd -> 2x2x2 brick of 128^3.
    // Per brick: 8 i-tiles(16) x 16 j-tiles(8) x 8 k-tiles(16) = 1024 blocks.
    const int bid = blockIdx.x;
    const int xcd = bid & 7;
    const int n = bid >> 3;              // 0..1023 per brick
    const int bi = (xcd >> 2) & 1;
    const int bj = (xcd >> 1) & 1;
    const int bk = xcd & 1;
    const int kt = n & 7;
    const int jt = (n >> 3) & 15;
    const int it = n >> 7;               // 0..7

    const int i0 = (bi << 7) + (it << 4);
    const int j0 = (bj << 7) + (jt << 3);
    const int k0 = (bk << 7) + (kt << 4);

    const int tid = threadIdx.x;
    const int kl = tid & 15;             // k within tile
    const int jl = (tid >> 4) & 7;       // j within tile
    const int ihalf = tid >> 7;          // 0/1: i sub-block of 8
    const int j = j0 + jl;
    const int k = k0 + kl;
    const float gj = (float)j, gk = (float)k;
    const int out_base = (i0 << 16) + (j << 8) + k;

    __shared__ float sv[LDSF];

    // ---- input bbox of this tile (block-uniform; affine => corners bound) --
    float mni =  1e30f, mxi = -1e30f;
    float mnj =  1e30f, mxj = -1e30f;
    float mnk =  1e30f, mxk = -1e30f;
#pragma unroll
    for (int c = 0; c < 8; ++c) {
        const float ci_ = (float)(i0 + ((c & 1) ? (TI - 1) : 0));
        const float cj_ = (float)(j0 + ((c & 2) ? (TJ - 1) : 0));
        const float ck_ = (float)(k0 + ((c & 4) ? (TK - 1) : 0));
        const float di = t0 * ci_ + t1 * cj_ + t2  * ck_ + t3;
        const float dj = t4 * ci_ + t5 * cj_ + t6  * ck_ + t7;
        const float dk = t8 * ci_ + t9 * cj_ + t10 * ck_ + t11;
        mni = fminf(mni, di); mxi = fmaxf(mxi, di);
        mnj = fminf(mnj, dj); mxj = fmaxf(mxj, dj);
        mnk = fminf(mnk, dk); mxk = fmaxf(mxk, dk);
    }
    // clamp -> floor -> pad (-1/+2 absorbs incremental-rounding drift and the
    // ceil corner + k-pair +1), exactly as the passing R12 kernel.
    int lo_i = (int)fminf(fmaxf(mni, 0.0f), 255.0f);
    int hi_i = (int)fminf(fmaxf(mxi, 0.0f), 255.0f);
    int lo_j = (int)fminf(fmaxf(mnj, 0.0f), 255.0f);
    int hi_j = (int)fminf(fmaxf(mxj, 0.0f), 255.0f);
    int lo_k = (int)fminf(fmaxf(mnk, 0.0f), 255.0f);
    int hi_k = (int)fminf(fmaxf(mxk, 0.0f), 255.0f);
    lo_i = min(max(lo_i - 1, 0), 252);
    lo_j = min(max(lo_j - 1, 0), 252);
    lo_k = min(max(lo_k - 1, 0), 252);
    hi_i = min(max(hi_i + 2, lo_i + 3), 255);
    hi_j = min(max(hi_j + 2, lo_j + 3), 255);
    hi_k = min(max(hi_k + 2, lo_k + 3), 255);
    const int Si = hi_i - lo_i + 1;
    const int Sj = hi_j - lo_j + 1;
    int Sk  = hi_k - lo_k + 1;
    int SkL = (Sk + 3) & ~3;             // staged k floats (16B chunk grid)
    // Shift k-window down if staging chunks would read past the volume end
    // (only possible at the extreme corner).  Window still covers [lo_k,hi_k].
    if (lo_k + SkL > 256) {
        lo_k = 256 - SkL;
        Sk = hi_k - lo_k + 1;
        SkL = (Sk + 3) & ~3;
    }
    int Pk = SkL;
    if ((Pk & 7) == 0) Pk += 4;          // Pk == 4 (mod 8): conflict-free-ish
    const int SjPk = Sj * Pk;
    const bool fits = (Si * SjPk <= LDSF) && (Sj <= 16) && (Sk <= 32);

    if (fits) {
        // -------- stage box into LDS (dwordx4, 2-deep pipelined) -----------
        {
            const int lj  = tid & 15;            // j-row
            const int c4  = (tid >> 4) & 7;      // 4-float chunk id
            const int li0 = tid >> 7;            // 0/1 -> i-plane parity
            const int kk  = c4 << 2;
            if (lj < Sj && kk < SkL) {
                const float* gp = vol + ((lo_i + li0) << 16)
                                      + ((lo_j + lj) << 8) + lo_k + kk;
                float* sp = sv + (li0 * Sj + lj) * Pk + kk;
                int li = li0;
                for (; li + 2 < Si; li += 4) {
                    const f4v a = *(const f4u*)gp;
                    const f4v b = *(const f4u*)(gp + (2 << 16));
                    *(f4u*)sp = a;
                    *(f4u*)(sp + 2 * SjPk) = b;
                    gp += 4 << 16;
                    sp += 4 * SjPk;
                }
                for (; li < Si; li += 2) {
                    *(f4u*)sp = *(const f4u*)gp;
                    gp += 2 << 16;
                    sp += 2 * SjPk;
                }
            }
        }
        __syncthreads();

        // -------- interp: 2 groups of 4 i-voxels per thread (verbatim) -----
#pragma unroll
        for (int IT = 0; IT < 2; ++IT) {
            const float gi_ = (float)(i0 + ihalf * 8 + IT * 4);
            float di_ = t0 * gi_ + t1 * gj + t2  * gk + t3;
            float dj_ = t4 * gi_ + t5 * gj + t6  * gk + t7;
            float dk_ = t8 * gi_ + t9 * gj + t10 * gk + t11;
#pragma unroll
            for (int s_ = 0; s_ < 4; ++s_) {
                const float cdi = fminf(fmaxf(di_, 0.0f), (float)(DD - 1));
                const float cdj = fminf(fmaxf(dj_, 0.0f), (float)(HH - 1));
                const float cdk = fminf(fmaxf(dk_, 0.0f), (float)(WW - 1));
                const int fi = (int)cdi;
                const int fj = (int)cdj;
                const int fk = (int)cdk;
                const int ci = min(fi + 1, DD - 1);
                const int cj = min(fj + 1, HH - 1);
                const int pk = min(fk, WW - 2);
                const float wi = cdi - (float)fi;
                const float wj = cdj - (float)fj;
                const float wk = cdk - (float)pk;
                const bool ok_ = (di_ >= 0.0f) & (di_ <= (float)(DD - 1)) &
                                 (dj_ >= 0.0f) & (dj_ <= (float)(HH - 1)) &
                                 (dk_ >= 0.0f) & (dk_ <= (float)(WW - 1));

                const int o_fi = (fi - lo_i) * SjPk;
                const int o_ci = (ci - lo_i) * SjPk;
                const int o_fj = (fj - lo_j) * Pk;
                const int o_cj = (cj - lo_j) * Pk;
                const int pl = pk - lo_k;

                const f2v v0 = *(const f2u*)(sv + o_fi + o_fj + pl);
                const f2v v1 = *(const f2u*)(sv + o_fi + o_cj + pl);
                const f2v v2 = *(const f2u*)(sv + o_ci + o_fj + pl);
                const f2v v3 = *(const f2u*)(sv + o_ci + o_cj + pl);

                const float c00 = v0.x + (v0.y - v0.x) * wk;
                const float c01 = v1.x + (v1.y - v1.x) * wk;
                const float c10 = v2.x + (v2.y - v2.x) * wk;
                const float c11 = v3.x + (v3.y - v3.x) * wk;
                const float c0  = c00 + (c01 - c00) * wj;
                const float c1  = c10 + (c11 - c10) * wj;
                const float val = c0 + (c1 - c0) * wi;

                __builtin_nontemporal_store(ok_ ? val : 0.0f,
                    &out[out_base + ((ihalf * 8 + IT * 4 + s_) << 16)]);

                di_ += t0; dj_ += t4; dk_ += t8;
            }
        }
    } else {
        // -------- fallback: per-voxel global gather (verbatim R12) ---------
#pragma unroll
        for (int IT = 0; IT < 2; ++IT) {
            const float gi_ = (float)(i0 + ihalf * 8 + IT * 4);
            float di_ = t0 * gi_ + t1 * gj + t2  * gk + t3;
            float dj_ = t4 * gi_ + t5 * gj + t6  * gk + t7;
            float dk_ = t8 * gi_ + t9 * gj + t10 * gk + t11;
#pragma unroll
            for (int s_ = 0; s_ < 4; ++s_) {
                const float cdi = fminf(fmaxf(di_, 0.0f), (float)(DD - 1));
                const float cdj = fminf(fmaxf(dj_, 0.0f), (float)(HH - 1));
                const float cdk = fminf(fmaxf(dk_, 0.0f), (float)(WW - 1));
                const int fi = (int)cdi;
                const int fj = (int)cdj;
                const int fk = (int)cdk;
                const int ci = min(fi + 1, DD - 1);
                const int cj = min(fj + 1, HH - 1);
                const int pk = min(fk, WW - 2);
                const float wi = cdi - (float)fi;
                const float wj = cdj - (float)fj;
                const float wk = cdk - (float)pk;
                const bool ok_ = (di_ >= 0.0f) & (di_ <= (float)(DD - 1)) &
                                 (dj_ >= 0.0f) & (dj_ <= (float)(HH - 1)) &
                                 (dk_ >= 0.0f) & (dk_ <= (float)(WW - 1));

                const int fi_o = fi << 16, ci_o = ci << 16;
                const int fj_o = fj << 8,  cj_o = cj << 8;
                const f2v v0 = *(const f2u*)(vol + (fi_o + fj_o + pk));
                const f2v v1 = *(const f2u*)(vol + (fi_o + cj_o + pk));
                const f2v v2 = *(const f2u*)(vol + (ci_o + fj_o + pk));
                const f2v v3 = *(const f2u*)(vol + (ci_o + cj_o + pk));

                const float c00 = v0.x + (v0.y - v0.x) * wk;
                const float c01 = v1.x + (v1.y - v1.x) * wk;
                const float c10 = v2.x + (v2.y - v2.x) * wk;
                const float c11 = v3.x + (v3.y - v3.x) * wk;
                const float c0  = c00 + (c01 - c00) * wj;
                const float c1  = c10 + (c11 - c10) * wj;
                const float val = c0 + (c1 - c0) * wi;

                __builtin_nontemporal_store(ok_ ? val : 0.0f,
                    &out[out_base + ((ihalf * 8 + IT * 4 + s_) << 16)]);

                di_ += t0; dj_ += t4; dk_ += t8;
            }
        }
    }
}

extern "C" void kernel_launch(void* const* d_in, const int* in_sizes, int n_in,
                              void* d_out, int out_size, void* d_ws, size_t ws_size,
                              hipStream_t stream) {
    const float* image_targ  = (const float*)d_in[0];
    const float* angle       = (const float*)d_in[1];
    const float* translation = (const float*)d_in[2];
    const float* ref_v2r     = (const float*)d_in[3];
    const float* flo_v2r     = (const float*)d_in[4];
    const float* cog         = (const float*)d_in[5];
    float* out = (float*)d_out;
    float* Tws = (float*)d_ws;   // 12 floats

    compute_T_kernel<<<1, 64, 0, stream>>>(angle, translation, ref_v2r,
                                           flo_v2r, cog, Tws);
    // 8192 blocks: 8 bricks x (8 i-tiles x 16 j-tiles x 8 k-tiles).
    warp_kernel<<<(DD / TI) * (HH / TJ) * (WW / TK), 256, 0, stream>>>(
        image_targ, Tws, out);
}